// Round 6
// baseline (78.925 us; speedup 1.0000x reference)
//
#include <hip/hip_runtime.h>
#include <math.h>

// VectorExpansionCalculator: per-edge radial basis (8 sines w/ cosine cutoff)
// outer-product with real spherical harmonics l=0..3 (n_max = 8,7,6,5).
// Output f32 blocks concat flat: [E,1,8] | [E,3,7] | [E,5,6] | [E,7,5].
// R1: scattered scalar stores -> 137us (store-request bound).
// R2: per-wave LDS staging -> coalesced dwordx4 -> 79us (4.9 TB/s).
// R3/R4: staged block0, native v_sin/v_cos, nontemporal stores -> 74.9us.
// R5: XCD swizzle -> 76.3us (refuted; reverted).
// R6 (this): persistent balanced-chunked grid (1024 blocks = 256 CU x 4,
//            contiguous task runs) — kills dispatch tail + amortizes setup.

#define RCUT 5.0f
#define EPSF 1e-12f

typedef float fx4 __attribute__((ext_vector_type(4)));

// Stage S floats/lane into wave-private LDS (linear [64][S]), then flush the
// wave's contiguous 64*S-float region with coalesced nontemporal 16B stores.
template <int S>
__device__ __forceinline__ void stage_flush(float* __restrict__ lw,
                                            const float* __restrict__ vals,
                                            int lane,
                                            fx4* __restrict__ g4) {
#pragma unroll
  for (int i = 0; i < S; ++i) lw[lane * S + i] = vals[i];
  // LDS is in-order per wave; compiler inserts lgkmcnt before dependent reads.
  const fx4* l4 = reinterpret_cast<const fx4*>(lw);
  constexpr int NF4 = 16 * S;                 // 64*S/4 16B-vectors
  constexpr int NITER = (NF4 + 63) / 64;
#pragma unroll
  for (int it = 0; it < NITER; ++it) {
    int k = lane + it * 64;
    if ((NF4 % 64 == 0) || k < NF4) __builtin_nontemporal_store(l4[k], &g4[k]);
  }
}

__global__ __launch_bounds__(256) void vexp_kernel(const float* __restrict__ v,
                                                   float* __restrict__ out, int E,
                                                   int ntask) {
  __shared__ fx4 lbuf[4][560];  // per-wave staging: 35*64 floats = 8960 B
  const int lane = threadIdx.x & 63;
  const int wave = threadIdx.x >> 6;
  const size_t E_ = (size_t)E;
  float* lw = reinterpret_cast<float*>(lbuf[wave]);
  fx4* l4 = lbuf[wave];

  // Balanced chunked persistent assignment: block b owns a CONTIGUOUS run of
  // 256-edge tasks (q or q+1 of them) -> address-local writes, no grid tail.
  const int nb = gridDim.x;
  const int b = blockIdx.x;
  const int q = ntask / nb, r = ntask % nb;
  const int cnt = q + (b < r ? 1 : 0);
  const long long start =
      (b < r) ? (long long)b * (q + 1)
              : (long long)r * (q + 1) + (long long)(b - r) * q;

  for (int j = 0; j < cnt; ++j) {
    const long long e0 = ((start + j) * 4 + wave) * 64;
    if (e0 >= E) continue;  // only possible in the final task's upper waves
    const bool fullwave = (e0 + 64 <= (long long)E);
    const int e = (int)e0 + lane;
    const bool valid = e < E;

    float xc = 0.0f, yc = 0.0f, zc = 0.0f;
    if (valid) {
      xc = v[3 * (size_t)e + 0];
      yc = v[3 * (size_t)e + 1];
      zc = v[3 * (size_t)e + 2];
    }

    float r2 = xc * xc + yc * yc + zc * zc;
    float rr = sqrtf(r2);
    float ir = 1.0f / (rr + EPSF);

    // ---- radial basis: rb[n] = fcut * sin((n+1)*pi*r/RCUT) / (r+eps) ----
    float theta = (3.14159265358979323846f / RCUT) * rr;
    float s = __sinf(theta);
    float c = __cosf(theta);
    float fcut = (rr < RCUT) ? 0.5f * (c + 1.0f) : 0.0f;
    float g = fcut * ir;

    float rb[8];
    {
      float twoc = 2.0f * c;
      float sp = 0.0f, sn = s;
      rb[0] = sn * g;
#pragma unroll
      for (int n = 1; n < 8; ++n) {
        float s2 = twoc * sn - sp;
        sp = sn;
        sn = s2;
        rb[n] = sn * g;
      }
    }

    // ---- unit direction + spherical harmonics ----
    float ux = xc * ir, uy = yc * ir, uz = zc * ir;
    float xx = ux * ux, yy = uy * uy, zz = uz * uz;

    const float c1 = 0.48860251190291992f;
    float sh1[3] = {c1 * uy, c1 * uz, c1 * ux};

    const float c2a = 1.09254843059207907f;
    const float c2b = 0.31539156525252001f;
    const float c2c = 0.54627421529603953f;
    float sh2[5] = {c2a * ux * uy, c2a * uy * uz, c2b * (2.0f * zz - xx - yy),
                    c2a * ux * uz, c2c * (xx - yy)};

    const float c3a = 0.59004358992664352f;
    const float c3b = 2.89061144264055405f;
    const float c3c = 0.45704579946446574f;
    const float c3d = 0.37317633259011546f;
    const float c3e = 1.44530572132027702f;
    float sh3[7] = {c3a * uy * (3.0f * xx - yy),
                    c3b * ux * uy * uz,
                    c3c * uy * (4.0f * zz - xx - yy),
                    c3d * uz * (2.0f * zz - 3.0f * xx - 3.0f * yy),
                    c3c * ux * (4.0f * zz - xx - yy),
                    c3e * uz * (xx - yy),
                    c3a * ux * (xx - 3.0f * yy)};

    float vals[35];

    // ---- block 0: [E,1,8] @ 0 — blocked [chunk][lane] fx4 layout in LDS ----
    const float y0c = 0.28209479177387814f;
    if (fullwave) {
      fx4 a0 = {y0c * rb[0], y0c * rb[1], y0c * rb[2], y0c * rb[3]};
      fx4 b0 = {y0c * rb[4], y0c * rb[5], y0c * rb[6], y0c * rb[7]};
      l4[lane] = a0;
      l4[64 + lane] = b0;
      fx4* g4 = reinterpret_cast<fx4*>(out + (size_t)e0 * 8);
#pragma unroll
      for (int it = 0; it < 2; ++it) {
        int k = lane + it * 64;
        int slot = ((k & 1) << 6) + (k >> 1);  // chunk k = edge k>>1, half k&1
        __builtin_nontemporal_store(l4[slot], &g4[k]);
      }
    } else if (valid) {
      float* o = out + (size_t)e * 8;
#pragma unroll
      for (int n = 0; n < 8; ++n) o[n] = y0c * rb[n];
    }

    // ---- block 1: [E,3,7] @ 8E ----
#pragma unroll
    for (int m = 0; m < 3; ++m)
#pragma unroll
      for (int n = 0; n < 7; ++n) vals[m * 7 + n] = sh1[m] * rb[n];
    if (fullwave) {
      stage_flush<21>(lw, vals, lane,
                      reinterpret_cast<fx4*>(out + 8 * E_ + (size_t)e0 * 21));
    } else if (valid) {
      float* o = out + 8 * E_ + (size_t)e * 21;
#pragma unroll
      for (int i2 = 0; i2 < 21; ++i2) o[i2] = vals[i2];
    }

    // ---- block 2: [E,5,6] @ 29E ----
#pragma unroll
    for (int m = 0; m < 5; ++m)
#pragma unroll
      for (int n = 0; n < 6; ++n) vals[m * 6 + n] = sh2[m] * rb[n];
    if (fullwave) {
      stage_flush<30>(lw, vals, lane,
                      reinterpret_cast<fx4*>(out + 29 * E_ + (size_t)e0 * 30));
    } else if (valid) {
      float* o = out + 29 * E_ + (size_t)e * 30;
#pragma unroll
      for (int i2 = 0; i2 < 30; ++i2) o[i2] = vals[i2];
    }

    // ---- block 3: [E,7,5] @ 59E ----
#pragma unroll
    for (int m = 0; m < 7; ++m)
#pragma unroll
      for (int n = 0; n < 5; ++n) vals[m * 5 + n] = sh3[m] * rb[n];
    if (fullwave) {
      stage_flush<35>(lw, vals, lane,
                      reinterpret_cast<fx4*>(out + 59 * E_ + (size_t)e0 * 35));
    } else if (valid) {
      float* o = out + 59 * E_ + (size_t)e * 35;
#pragma unroll
      for (int i2 = 0; i2 < 35; ++i2) o[i2] = vals[i2];
    }
  }
}

extern "C" void kernel_launch(void* const* d_in, const int* in_sizes, int n_in,
                              void* d_out, int out_size, void* d_ws, size_t ws_size,
                              hipStream_t stream) {
  const float* v = (const float*)d_in[0];
  float* out = (float*)d_out;
  int E = in_sizes[0] / 3;
  int waves = (E + 63) / 64;
  int ntask = (waves + 3) / 4;          // 256-edge tasks
  int grid = ntask < 1024 ? ntask : 1024;  // 256 CU x 4 blocks/CU resident
  vexp_kernel<<<grid, 256, 0, stream>>>(v, out, E, ntask);
}

// Round 7
// 74.671 us; speedup vs baseline: 1.0570x; 1.0570x over previous
//
#include <hip/hip_runtime.h>
#include <math.h>

// VectorExpansionCalculator: per-edge radial basis (8 sines w/ cosine cutoff)
// outer-product with real spherical harmonics l=0..3 (n_max = 8,7,6,5).
// Output f32 blocks concat flat: [E,1,8] | [E,3,7] | [E,5,6] | [E,7,5].
// R1: scattered scalar stores -> 137us. R2: LDS staging -> 79us.
// R3/R4: +sinf native, +nt stores, staged s0 -> 74.9us (best).
// R5: XCD swizzle -> 76.3us (refuted). R6: persistent grid -> 78.9us (refuted).
// R7 (this): one kernel PER SECTION, launched sequentially. Each kernel is a
// single contiguous write stream (same shape as the 6.8 TB/s fill kernel),
// instead of every wave dribbling into 4 far-apart regions. v re-read is
// L3-resident after kernel 1; compute redone per kernel (VALU ~5%, hidden).

#define RCUT 5.0f
#define EPSF 1e-12f

typedef float fx4 __attribute__((ext_vector_type(4)));

__device__ __forceinline__ void radial(float rr, float ir, float rb[8]) {
  float theta = (3.14159265358979323846f / RCUT) * rr;
  float s = __sinf(theta);
  float c = __cosf(theta);
  float fcut = (rr < RCUT) ? 0.5f * (c + 1.0f) : 0.0f;
  float g = fcut * ir;
  float twoc = 2.0f * c;
  float sp = 0.0f, sn = s;
  rb[0] = sn * g;
#pragma unroll
  for (int n = 1; n < 8; ++n) {
    float s2 = twoc * sn - sp;
    sp = sn;
    sn = s2;
    rb[n] = sn * g;
  }
}

// ---- section 0: [E,1,8]. Thread-per-fx4: tid -> edge tid>>1, half tid&1.
// Redundant rb compute per edge pair; zero LDS; perfectly coalesced stores.
__global__ __launch_bounds__(256) void vexp_s0(const float* __restrict__ v,
                                               float* __restrict__ out,
                                               long long n4) {
  long long tid = (long long)blockIdx.x * blockDim.x + threadIdx.x;
  if (tid >= n4) return;
  long long e = tid >> 1;
  int half = (int)(tid & 1);
  float x = v[3 * e + 0], y = v[3 * e + 1], z = v[3 * e + 2];
  float rr = sqrtf(x * x + y * y + z * z);
  float ir = 1.0f / (rr + EPSF);
  float rb[8];
  radial(rr, ir, rb);
  const float y0c = 0.28209479177387814f;
  int o = 4 * half;
  fx4 val = {y0c * rb[o], y0c * rb[o + 1], y0c * rb[o + 2], y0c * rb[o + 3]};
  __builtin_nontemporal_store(val, &reinterpret_cast<fx4*>(out)[tid]);
}

// ---- sections 1..3: stage 64 edges x S floats in wave-private LDS, flush
// as one contiguous run of nontemporal 16B stores.
template <int L>
__global__ __launch_bounds__(256) void vexp_sec(const float* __restrict__ v,
                                                float* __restrict__ secbase,
                                                int E) {
  constexpr int M = 2 * L + 1;        // SH count
  constexpr int NM = 8 - L;           // n_max for this l
  constexpr int S = M * NM;           // floats per edge
  __shared__ fx4 lbuf[4][16 * S];
  const int lane = threadIdx.x & 63;
  const int wave = threadIdx.x >> 6;
  const long long e0 = ((long long)blockIdx.x * 4 + wave) * 64;
  if (e0 >= E) return;
  const bool fullwave = (e0 + 64 <= (long long)E);
  const int e = (int)e0 + lane;
  const bool valid = e < E;

  float x = 0.0f, y = 0.0f, z = 0.0f;
  if (valid) {
    x = v[3 * (size_t)e + 0];
    y = v[3 * (size_t)e + 1];
    z = v[3 * (size_t)e + 2];
  }
  float rr = sqrtf(x * x + y * y + z * z);
  float ir = 1.0f / (rr + EPSF);
  float rb[8];
  radial(rr, ir, rb);

  float ux = x * ir, uy = y * ir, uz = z * ir;
  float xx = ux * ux, yy = uy * uy, zz = uz * uz;

  float sh[M];
  if constexpr (L == 1) {
    const float c1 = 0.48860251190291992f;
    sh[0] = c1 * uy;
    sh[1] = c1 * uz;
    sh[2] = c1 * ux;
  } else if constexpr (L == 2) {
    const float c2a = 1.09254843059207907f;
    const float c2b = 0.31539156525252001f;
    const float c2c = 0.54627421529603953f;
    sh[0] = c2a * ux * uy;
    sh[1] = c2a * uy * uz;
    sh[2] = c2b * (2.0f * zz - xx - yy);
    sh[3] = c2a * ux * uz;
    sh[4] = c2c * (xx - yy);
  } else {
    const float c3a = 0.59004358992664352f;
    const float c3b = 2.89061144264055405f;
    const float c3c = 0.45704579946446574f;
    const float c3d = 0.37317633259011546f;
    const float c3e = 1.44530572132027702f;
    sh[0] = c3a * uy * (3.0f * xx - yy);
    sh[1] = c3b * ux * uy * uz;
    sh[2] = c3c * uy * (4.0f * zz - xx - yy);
    sh[3] = c3d * uz * (2.0f * zz - 3.0f * xx - 3.0f * yy);
    sh[4] = c3c * ux * (4.0f * zz - xx - yy);
    sh[5] = c3e * uz * (xx - yy);
    sh[6] = c3a * ux * (xx - 3.0f * yy);
  }

  float vals[S];
#pragma unroll
  for (int m = 0; m < M; ++m)
#pragma unroll
    for (int n = 0; n < NM; ++n) vals[m * NM + n] = sh[m] * rb[n];

  if (fullwave) {
    float* lw = reinterpret_cast<float*>(lbuf[wave]);
#pragma unroll
    for (int i = 0; i < S; ++i) lw[lane * S + i] = vals[i];
    const fx4* l4 = lbuf[wave];
    fx4* g4 = reinterpret_cast<fx4*>(secbase + (size_t)e0 * S);
    constexpr int NF4 = 16 * S;
    constexpr int NITER = (NF4 + 63) / 64;
#pragma unroll
    for (int it = 0; it < NITER; ++it) {
      int k = lane + it * 64;
      if ((NF4 % 64 == 0) || k < NF4) __builtin_nontemporal_store(l4[k], &g4[k]);
    }
  } else if (valid) {
    float* o = secbase + (size_t)e * S;
#pragma unroll
    for (int i = 0; i < S; ++i) o[i] = vals[i];
  }
}

extern "C" void kernel_launch(void* const* d_in, const int* in_sizes, int n_in,
                              void* d_out, int out_size, void* d_ws, size_t ws_size,
                              hipStream_t stream) {
  const float* v = (const float*)d_in[0];
  float* out = (float*)d_out;
  int E = in_sizes[0] / 3;
  size_t E_ = (size_t)E;

  long long n4 = 2LL * E;  // fx4 units in section 0
  int grid0 = (int)((n4 + 255) / 256);
  vexp_s0<<<grid0, 256, 0, stream>>>(v, out, n4);

  int waves = (E + 63) / 64;
  int grid = (waves + 3) / 4;  // 4 waves per 256-thread block
  vexp_sec<1><<<grid, 256, 0, stream>>>(v, out + 8 * E_, E);
  vexp_sec<2><<<grid, 256, 0, stream>>>(v, out + 29 * E_, E);
  vexp_sec<3><<<grid, 256, 0, stream>>>(v, out + 59 * E_, E);
}

// Round 8
// 73.201 us; speedup vs baseline: 1.0782x; 1.0201x over previous
//
#include <hip/hip_runtime.h>
#include <math.h>

// VectorExpansionCalculator: per-edge radial basis (8 sines w/ cosine cutoff)
// outer-product with real spherical harmonics l=0..3 (n_max = 8,7,6,5).
// Output f32 blocks concat flat: [E,1,8] | [E,3,7] | [E,5,6] | [E,7,5].
// R1: scattered stores 137us. R2: LDS staging 79us. R3/R4: native sin, nt
// stores, staged s0 -> 74.9us. R5 XCD swizzle: refuted. R6 persistent grid:
// refuted. R7 one-kernel-per-section: 74.7us (null — per-section gain eaten
// by 3 kernel-boundary drains).
// R8 (this): FUSE R7's four single-stream kernels into ONE launch, block-range
// partitioned (bid/gsec selects section). Same pure-stream write shape, zero
// internal boundaries.

#define RCUT 5.0f
#define EPSF 1e-12f

typedef float fx4 __attribute__((ext_vector_type(4)));

__device__ __forceinline__ void radial(float rr, float ir, float rb[8]) {
  float theta = (3.14159265358979323846f / RCUT) * rr;
  float s = __sinf(theta);
  float c = __cosf(theta);
  float fcut = (rr < RCUT) ? 0.5f * (c + 1.0f) : 0.0f;
  float g = fcut * ir;
  float twoc = 2.0f * c;
  float sp = 0.0f, sn = s;
  rb[0] = sn * g;
#pragma unroll
  for (int n = 1; n < 8; ++n) {
    float s2 = twoc * sn - sp;
    sp = sn;
    sn = s2;
    rb[n] = sn * g;
  }
}

// Sections 1..3: one 256-edge task per block (4 waves x 64 edges); stage
// 64 x S floats in wave-private LDS, flush as contiguous nontemporal stores.
template <int L>
__device__ __forceinline__ void do_section(const float* __restrict__ v,
                                           float* __restrict__ secbase, int E,
                                           int task, fx4* __restrict__ l4,
                                           int lane, int wave) {
  constexpr int M = 2 * L + 1;  // SH count
  constexpr int NM = 8 - L;     // n_max for this l
  constexpr int S = M * NM;     // floats per edge
  const long long e0 = ((long long)task * 4 + wave) * 64;
  if (e0 >= E) return;
  const bool fullwave = (e0 + 64 <= (long long)E);
  const int e = (int)e0 + lane;
  const bool valid = e < E;

  float x = 0.0f, y = 0.0f, z = 0.0f;
  if (valid) {
    x = v[3 * (size_t)e + 0];
    y = v[3 * (size_t)e + 1];
    z = v[3 * (size_t)e + 2];
  }
  float rr = sqrtf(x * x + y * y + z * z);
  float ir = 1.0f / (rr + EPSF);
  float rb[8];
  radial(rr, ir, rb);

  float ux = x * ir, uy = y * ir, uz = z * ir;
  float xx = ux * ux, yy = uy * uy, zz = uz * uz;

  float sh[M];
  if constexpr (L == 1) {
    const float c1 = 0.48860251190291992f;
    sh[0] = c1 * uy;
    sh[1] = c1 * uz;
    sh[2] = c1 * ux;
  } else if constexpr (L == 2) {
    const float c2a = 1.09254843059207907f;
    const float c2b = 0.31539156525252001f;
    const float c2c = 0.54627421529603953f;
    sh[0] = c2a * ux * uy;
    sh[1] = c2a * uy * uz;
    sh[2] = c2b * (2.0f * zz - xx - yy);
    sh[3] = c2a * ux * uz;
    sh[4] = c2c * (xx - yy);
  } else {
    const float c3a = 0.59004358992664352f;
    const float c3b = 2.89061144264055405f;
    const float c3c = 0.45704579946446574f;
    const float c3d = 0.37317633259011546f;
    const float c3e = 1.44530572132027702f;
    sh[0] = c3a * uy * (3.0f * xx - yy);
    sh[1] = c3b * ux * uy * uz;
    sh[2] = c3c * uy * (4.0f * zz - xx - yy);
    sh[3] = c3d * uz * (2.0f * zz - 3.0f * xx - 3.0f * yy);
    sh[4] = c3c * ux * (4.0f * zz - xx - yy);
    sh[5] = c3e * uz * (xx - yy);
    sh[6] = c3a * ux * (xx - 3.0f * yy);
  }

  float vals[S];
#pragma unroll
  for (int m = 0; m < M; ++m)
#pragma unroll
    for (int n = 0; n < NM; ++n) vals[m * NM + n] = sh[m] * rb[n];

  if (fullwave) {
    float* lw = reinterpret_cast<float*>(l4);
#pragma unroll
    for (int i = 0; i < S; ++i) lw[lane * S + i] = vals[i];
    fx4* g4 = reinterpret_cast<fx4*>(secbase + (size_t)e0 * S);
    constexpr int NF4 = 16 * S;
    constexpr int NITER = (NF4 + 63) / 64;
#pragma unroll
    for (int it = 0; it < NITER; ++it) {
      int k = lane + it * 64;
      if ((NF4 % 64 == 0) || k < NF4)
        __builtin_nontemporal_store(l4[k], &g4[k]);
    }
  } else if (valid) {
    float* o = secbase + (size_t)e * S;
#pragma unroll
    for (int i = 0; i < S; ++i) o[i] = vals[i];
  }
}

__global__ __launch_bounds__(256) void vexp_fused(const float* __restrict__ v,
                                                  float* __restrict__ out,
                                                  int E, int gsec) {
  __shared__ fx4 lbuf[4][560];  // 35.8 KB -> 4 blocks/CU
  const int bid = blockIdx.x;
  const int lane = threadIdx.x & 63;
  const int wave = threadIdx.x >> 6;
  const size_t E_ = (size_t)E;

  if (bid < gsec) {
    // ---- section 0: [E,1,8]. Thread-per-fx4, 2 grid-stride iters, no LDS.
    const long long n4 = 2LL * E;
    const float y0c = 0.28209479177387814f;
#pragma unroll
    for (int k = 0; k < 2; ++k) {
      long long t = (long long)bid * 256 + threadIdx.x + (long long)k * gsec * 256;
      if (t < n4) {
        long long e = t >> 1;
        int half = (int)(t & 1);
        float x = v[3 * e + 0], y = v[3 * e + 1], z = v[3 * e + 2];
        float rr = sqrtf(x * x + y * y + z * z);
        float ir = 1.0f / (rr + EPSF);
        float rb[8];
        radial(rr, ir, rb);
        int o = 4 * half;
        fx4 val = {y0c * rb[o], y0c * rb[o + 1], y0c * rb[o + 2],
                   y0c * rb[o + 3]};
        __builtin_nontemporal_store(val, &reinterpret_cast<fx4*>(out)[t]);
      }
    }
  } else if (bid < 2 * gsec) {
    do_section<1>(v, out + 8 * E_, E, bid - gsec, lbuf[wave], lane, wave);
  } else if (bid < 3 * gsec) {
    do_section<2>(v, out + 29 * E_, E, bid - 2 * gsec, lbuf[wave], lane, wave);
  } else {
    do_section<3>(v, out + 59 * E_, E, bid - 3 * gsec, lbuf[wave], lane, wave);
  }
}

extern "C" void kernel_launch(void* const* d_in, const int* in_sizes, int n_in,
                              void* d_out, int out_size, void* d_ws, size_t ws_size,
                              hipStream_t stream) {
  const float* v = (const float*)d_in[0];
  float* out = (float*)d_out;
  int E = in_sizes[0] / 3;
  int waves = (E + 63) / 64;
  int gsec = (waves + 3) / 4;  // 256-edge tasks per section
  vexp_fused<<<4 * gsec, 256, 0, stream>>>(v, out, E, gsec);
}